// Round 19
// baseline (2003.948 us; speedup 1.0000x reference)
//
#include <hip/hip_runtime.h>
#include <math.h>

// Problem constants
constexpr int Bn  = 4;
constexpr int T   = 6;
constexpr int CIN = 3;
constexpr int CH  = 64;
constexpr int IMG = 128;
constexpr int HW  = IMG * IMG;          // 16384

// Channels-last bf16 buffers, halo 4 each side: [b][136][136][Cstride]
constexpr int CLY = 136;
constexpr long CLN = 4L * CLY * CLY * 64;    // 4,734,976 ushorts (64-ch buffer)
constexpr long CLNX = 4L * CLY * CLY * 32;   // 2,367,488 ushorts (32-ch buffer)

typedef short bf16x8 __attribute__((ext_vector_type(8)));
typedef float f32x4  __attribute__((ext_vector_type(4)));

__device__ __forceinline__ unsigned short f2bf(float f) {
    union { float f; unsigned int u; } v; v.f = f;
    unsigned int u = v.u;
    unsigned int r = (u + 0x7FFFu + ((u >> 16) & 1u)) >> 16;   // RNE
    return (unsigned short)r;
}
__device__ __forceinline__ float bf2f(unsigned short s) {
    union { unsigned int u; float f; } v; v.u = ((unsigned int)s) << 16;
    return v.f;
}
__device__ __forceinline__ float sigmoidf_(float v) { return 1.f / (1.f + __expf(-v)); }
__device__ __forceinline__ float tanhf_(float v)    { return 1.f - 2.f / (1.f + __expf(2.f * v)); }

// ---------------------------------------------------------------------------
// Weight transform: OIHW fp32 -> MFMA A-frag bf16, cog-major frag layout:
//   frag f = ((cog*KK + kyx)*NCIC + cic)*4 + c ; co = c*16+(lane&15),
//   ci_new = cic*32 + (lane>>4)*8 + j ; ci_new<64 -> h, else input.
// ---------------------------------------------------------------------------
__global__ void xform_w(const float* __restrict__ wA, const float* __restrict__ wB,
                        unsigned short* __restrict__ dst,
                        int K, int C0, int NCIC, int NG) {
    int idx   = blockIdx.x * 256 + threadIdx.x;
    int total = NG * K * K * NCIC * 4 * 64;
    if (idx >= total) return;
    int CI   = C0 + 64;
    int KK   = K * K;
    int lane = idx & 63;
    int rest = idx >> 6;
    int c    = rest & 3; rest >>= 2;
    int cic  = rest % NCIC; rest /= NCIC;
    int kyx  = rest % KK;
    int cog  = rest / KK;
    const float* w = cog ? wB : wA;
    int co = c * 16 + (lane & 15);
    union { unsigned short u[8]; uint4 q; } t;
    #pragma unroll
    for (int j = 0; j < 8; ++j) {
        int ci_new = cic * 32 + ((lane >> 4) * 8) + j;
        int ci_o   = (ci_new < 64) ? (C0 + ci_new) : (ci_new - 64);
        bool valid = (ci_new < 64) || (ci_new - 64 < C0);
        float f = valid ? w[((long)co * CI + ci_o) * KK + kyx] : 0.f;
        t.u[j] = f2bf(f);
    }
    *(uint4*)(dst + (long)(idx >> 6) * 8 * 64 + lane * 8) = t.q;
}

// ---------------------------------------------------------------------------
// Build a channels-last bf16 buffer from NCHW fp32 (stride CST channels)
// ---------------------------------------------------------------------------
__global__ void build_cl(const float* __restrict__ src, long bstride, int C0,
                         unsigned short* __restrict__ dst, int NG, int CST) {
    int i    = blockIdx.x * 256 + threadIdx.x;
    int px   = i & 16383;
    int rest = i >> 14;
    int g    = rest % NG;
    int b    = rest / NG;
    int y    = px >> 7, x = px & 127;
    union { unsigned short u[8]; uint4 q; } t;
    #pragma unroll
    for (int j = 0; j < 8; ++j) {
        int ci  = g * 8 + j;
        float f = (ci < C0) ? src[(long)b * bstride + (long)ci * HW + px] : 0.f;
        t.u[j] = f2bf(f);
    }
    long off = (((long)b * CLY + 4 + y) * CLY + 4 + x) * CST + g * 8;
    *(uint4*)(dst + off) = t.q;
}

// ---------------------------------------------------------------------------
// Unpack CLH (bf16 ch-last) -> H fp32 NCHW (final output form)
// ---------------------------------------------------------------------------
__global__ void unpack_h(const unsigned short* __restrict__ clh, float* __restrict__ H) {
    int i  = blockIdx.x * 256 + threadIdx.x;   // 4*16384 threads
    int b  = i >> 14, px = i & 16383;
    int y  = px >> 7, x = px & 127;
    const unsigned short* p = clh + (((long)b * CLY + 4 + y) * CLY + 4 + x) * 64;
    float* Hb = H + (long)b * 64 * HW + px;
    #pragma unroll
    for (int g = 0; g < 8; ++g) {
        union { unsigned short us[8]; uint4 q; } t;
        t.q = *(const uint4*)(p + g * 8);
        #pragma unroll
        for (int j = 0; j < 8; ++j)
            Hb[(long)(g * 8 + j) * HW] = bf2f(t.us[j]);
    }
}

// ---------------------------------------------------------------------------
// L0 conv (K=3, CST=32): weights LDS-staged per kyx, B global (r15 exact).
// ---------------------------------------------------------------------------
template<int K, int NCIC, int S, int MODE, int CST>
__global__ __launch_bounds__(256)
void conv_l0(const unsigned short* __restrict__ clh,
             const unsigned short* __restrict__ clin,
             const unsigned short* __restrict__ wt,
             const float* __restrict__ bias_a,
             const float* __restrict__ bias_b,
             unsigned short* __restrict__ ubuf,
             unsigned short* __restrict__ clh2,
             unsigned short* __restrict__ clhL)
{
    constexpr int HOFF = 4 - K / 2;
    constexpr int KK   = K * K;
    constexpr int NF   = NCIC * 4;
    __shared__ unsigned short alds[2][NF * 512];

    int w    = threadIdx.x >> 6;
    int lane = threadIdx.x & 63;
    int cog  = (MODE == 0) ? blockIdx.y : 0;
    int m    = blockIdx.x;
    int k8   = m & 7;
    int q    = m >> 3;
    int b    = k8 >> 1;
    int y, x0;
    if (S == 4) { y = (k8 & 1) * 64 + (q >> 1) * 4 + w; x0 = (q & 1) * 64; }
    else        { y = (k8 & 1) * 64 + (q >> 2) * 4 + w; x0 = (q & 3) * 32; }
    int n  = lane & 15;
    int kg = lane >> 4;

    f32x4 acc[4][S];
    #pragma unroll
    for (int c = 0; c < 4; ++c)
        #pragma unroll
        for (int s = 0; s < S; ++s)
            acc[c][s] = (f32x4){0.f, 0.f, 0.f, 0.f};

    long rbh = ((long)(b * CLY + HOFF + y) * CLY + HOFF + x0 + n) * 64 + kg * 8;
    long rbi = ((long)(b * CLY + HOFF + y) * CLY + HOFF + x0 + n) * CST + kg * 8;
    const unsigned short* wcog = wt + (long)cog * KK * NF * 512;

    #define STAGEW(bi, kyx_) do {                                              \
        const unsigned short* _src = wcog + (long)(kyx_) * NF * 512;           \
        _Pragma("unroll")                                                      \
        for (int j = 0; j < NCIC; ++j) {                                       \
            int f = j * 4 + w;                                                 \
            __builtin_amdgcn_global_load_lds(                                  \
                (const __attribute__((address_space(1))) void*)(_src + f * 512 + lane * 8), \
                (__attribute__((address_space(3))) void*)(&alds[bi][f * 512]), \
                16, 0, 0);                                                     \
        }                                                                      \
    } while (0)

    STAGEW(0, 0);
    int cur = 0;
    for (int kyx = 0; kyx < KK; ++kyx) {
        if (kyx + 1 < KK) {
            STAGEW(cur ^ 1, kyx + 1);
            asm volatile("s_waitcnt vmcnt(%0)" :: "n"(NCIC) : "memory");
        } else {
            asm volatile("s_waitcnt vmcnt(0)" ::: "memory");
        }
        __builtin_amdgcn_s_barrier();
        asm volatile("" ::: "memory");

        int ky = kyx / K;
        int kx = kyx - ky * K;
        long offh = rbh + (long)(ky * CLY + kx) * 64;
        long offi = rbi + (long)(ky * CLY + kx) * CST;
        #pragma unroll
        for (int cic = 0; cic < NCIC; ++cic) {
            bf16x8 bfr[S], afr[4];
            #pragma unroll
            for (int s = 0; s < S; ++s) {
                if (cic < 2) bfr[s] = *(const bf16x8*)(clh  + offh + s * 16 * 64  + cic * 32);
                else         bfr[s] = *(const bf16x8*)(clin + offi + s * 16 * CST + (cic - 2) * 32);
            }
            #pragma unroll
            for (int c = 0; c < 4; ++c)
                afr[c] = *(const bf16x8*)(&alds[cur][(cic * 4 + c) * 512 + lane * 8]);
            #pragma unroll
            for (int c = 0; c < 4; ++c)
                #pragma unroll
                for (int s = 0; s < S; ++s)
                    acc[c][s] = __builtin_amdgcn_mfma_f32_16x16x32_bf16(afr[c], bfr[s], acc[c][s], 0, 0, 0);
        }
        asm volatile("" ::: "memory");
        __builtin_amdgcn_s_barrier();
        cur ^= 1;
    }
    #undef STAGEW

    #pragma unroll
    for (int coc = 0; coc < 4; ++coc) {
        int co_l = coc * 16 + kg * 4;
        #pragma unroll
        for (int s = 0; s < S; ++s) {
            int x = x0 + s * 16 + n;
            f32x4 v = acc[coc][s];
            long cloff = (((long)b * CLY + 4 + y) * CLY + 4 + x) * 64 + co_l;
            if (MODE == 0) {
                if (cog == 0) {
                    union { unsigned short us[4]; unsigned long long d; } t;
                    #pragma unroll
                    for (int rr = 0; rr < 4; ++rr)
                        t.us[rr] = f2bf(sigmoidf_(v[rr] + bias_a[co_l + rr]));
                    *(unsigned long long*)(ubuf + (((long)b * HW + y * IMG + x) * 64 + co_l)) = t.d;
                } else {
                    union { unsigned short us[4]; unsigned long long d; } hh, t;
                    hh.d = *(const unsigned long long*)(clh + cloff);
                    #pragma unroll
                    for (int rr = 0; rr < 4; ++rr) {
                        float rv = sigmoidf_(v[rr] + bias_b[co_l + rr]);
                        t.us[rr] = f2bf(bf2f(hh.us[rr]) * rv);
                    }
                    *(unsigned long long*)(clh2 + cloff) = t.d;
                }
            } else {
                union { unsigned short us[4]; unsigned long long d; } uu, hh, t;
                uu.d = *(const unsigned long long*)(ubuf + (((long)b * HW + y * IMG + x) * 64 + co_l));
                hh.d = *(const unsigned long long*)(clhL + cloff);
                #pragma unroll
                for (int rr = 0; rr < 4; ++rr) {
                    float o  = tanhf_(v[rr] + bias_a[co_l + rr]);
                    float hv = bf2f(hh.us[rr]);
                    float uv = bf2f(uu.us[rr]);
                    t.us[rr] = f2bf(hv + uv * (o - hv));
                }
                *(unsigned long long*)(clhL + cloff) = t.d;
            }
        }
    }
}

// ---------------------------------------------------------------------------
// K=5/7 conv — r15 structure, D=6 A-prefetch + setprio around the MFMA sweep.
//   Block = 8 waves (512 thr) = 4 rows x 32 px x 64 co (x2 gates MODE0).
//   Wave tile = 2 rows x 32 px x (MODE0: 32 co | MODE1: 16 co).
//   B tile in LDS [cg][row][px]x16B, SUBTP-padded (stride ≡ 0 mod 128B, 0
//   conflicts); tile[2] dbuf, stage(p+1) before compute(p), counted vmcnt.
//   Flattened tap loop loads A(t+6) before the MFMAs of A(t).
//   XCD swizzle: k8=blockIdx.x&7 -> (b=k8>>1, 64-row half k8&1).
// ---------------------------------------------------------------------------
template<int K, int MODE>
__global__ __launch_bounds__(512, 4)
void conv_db(const unsigned short* __restrict__ clh,
             const unsigned short* __restrict__ clin,
             const unsigned short* __restrict__ wt,
             const float* __restrict__ bias_a,
             const float* __restrict__ bias_b,
             unsigned short* __restrict__ ubuf,
             unsigned short* __restrict__ clh2,
             unsigned short* __restrict__ clhL)
{
    constexpr int HOFF = 4 - K / 2;
    constexpr int KK   = K * K;
    constexpr int ROWS = K + 3;
    constexpr int PXT  = 31 + K;
    constexpr int SUBT = ROWS * PXT;
    constexpr int SUBTP = (SUBT + 7) & ~7;      // stride ≡ 0 mod 128B
    constexpr int NCHUNK = 4 * SUBTP;
    constexpr int NGRP = NCHUNK / 64;
    constexpr int VCNT = NGRP / 8;
    constexpr int NCW = (MODE == 0) ? 2 : 1;
    constexpr int D   = 6;                      // A-prefetch depth (taps)

    __shared__ __align__(16) unsigned char tile[2][NCHUNK * 16];

    int tid  = threadIdx.x;
    int w    = tid >> 6;
    int lane = tid & 63;
    int cog  = (MODE == 0) ? (w >> 2) : 0;
    int cb   = (MODE == 0) ? ((w >> 1) & 1) * 2 : (w >> 1);
    int rp   = w & 1;
    int m    = blockIdx.x;
    int k8   = m & 7;
    int t8   = m >> 3;
    int b    = k8 >> 1;
    int y0   = (k8 & 1) * 64 + (t8 >> 2) * 4;
    int x0   = (t8 & 3) * 32;
    int n    = lane & 15;
    int kg   = lane >> 4;

    f32x4 acc[NCW][2][2];
    #pragma unroll
    for (int c = 0; c < NCW; ++c)
        #pragma unroll
        for (int rr = 0; rr < 2; ++rr)
            #pragma unroll
            for (int s = 0; s < 2; ++s)
                acc[c][rr][s] = (f32x4){0.f, 0.f, 0.f, 0.f};

    const unsigned short* wbase = wt + (long)cog * KK * 16 * 512;

    #define STAGE(bi, ph_) do {                                                \
        const unsigned short* sp_ = ((ph_) < 2) ? clh : clin;                  \
        int half_ = ((ph_) & 1) * 32;                                          \
        _Pragma("unroll 1")                                                    \
        for (int g = w; g < NGRP; g += 8) {                                    \
            int c_  = g * 64 + lane;                                           \
            int cg  = c_ / SUBTP;                                              \
            int rem = c_ - cg * SUBTP;                                         \
            int r   = rem / PXT;                                               \
            int px  = rem - r * PXT;                                           \
            const unsigned short* src_ = sp_ +                                 \
                (((long)(b * CLY + HOFF + y0 + r)) * CLY + (HOFF + x0 + px)) * 64 \
                + half_ + cg * 8;                                              \
            __builtin_amdgcn_global_load_lds(                                  \
                (const __attribute__((address_space(1))) void*)src_,           \
                (__attribute__((address_space(3))) void*)(&tile[bi][g * 64 * 16]), \
                16, 0, 0);                                                     \
        }                                                                      \
    } while (0)

    int cur = 0;
    STAGE(0, 0);
    #pragma unroll 1
    for (int ph = 0; ph < 4; ++ph) {
        if (ph < 3) {
            STAGE(cur ^ 1, ph + 1);
            asm volatile("s_waitcnt vmcnt(%0)" :: "n"(VCNT) : "memory");
        } else {
            asm volatile("s_waitcnt vmcnt(0)" ::: "memory");
        }
        __builtin_amdgcn_s_barrier();
        asm volatile("" ::: "memory");

        const unsigned char* tb = tile[cur];
        // A-frag base for this phase; per-tap stride = 16 frags * 512 us
        const unsigned short* wph = wbase + (long)(4 * ph + cb) * 512 + lane * 8;

        // prime prefetch pipeline: taps 0..D-1
        bf16x8 apre[D][NCW];
        #pragma unroll
        for (int tt = 0; tt < D; ++tt)
            #pragma unroll
            for (int c = 0; c < NCW; ++c)
                apre[tt][c] = *(const bf16x8*)(wph + (long)tt * 8192 + c * 512);

        __builtin_amdgcn_s_setprio(1);
        #pragma unroll
        for (int t = 0; t < KK; ++t) {
            constexpr int PXB = PXT * 16;
            int slot = t % D;                    // static after full unroll
            bf16x8 aC[NCW];
            #pragma unroll
            for (int c = 0; c < NCW; ++c) aC[c] = apre[slot][c];
            if (t + D < KK) {
                #pragma unroll
                for (int c = 0; c < NCW; ++c)
                    apre[slot][c] = *(const bf16x8*)(wph + (long)(t + D) * 8192 + c * 512);
            }
            int ky = t / K, kx = t - (t / K) * K;
            const unsigned char* row0 = tb + (kg * SUBTP + (rp * 2 + 0 + ky) * PXT) * 16;
            const unsigned char* row1 = row0 + PXB;
            bf16x8 bv[2][2];
            #pragma unroll
            for (int s = 0; s < 2; ++s) {
                bv[0][s] = *(const bf16x8*)(row0 + (kx + s * 16 + n) * 16);
                bv[1][s] = *(const bf16x8*)(row1 + (kx + s * 16 + n) * 16);
            }
            #pragma unroll
            for (int c = 0; c < NCW; ++c)
                #pragma unroll
                for (int rr = 0; rr < 2; ++rr)
                    #pragma unroll
                    for (int s = 0; s < 2; ++s)
                        acc[c][rr][s] = __builtin_amdgcn_mfma_f32_16x16x32_bf16(aC[c], bv[rr][s], acc[c][rr][s], 0, 0, 0);
        }
        __builtin_amdgcn_s_setprio(0);
        asm volatile("" ::: "memory");
        __builtin_amdgcn_s_barrier();
        cur ^= 1;
    }
    #undef STAGE

    // ---- epilogue ----
    #pragma unroll
    for (int c = 0; c < NCW; ++c) {
        int co_l = (cb + c) * 16 + kg * 4;
        #pragma unroll
        for (int rr = 0; rr < 2; ++rr) {
            int yy = y0 + rp * 2 + rr;
            #pragma unroll
            for (int s = 0; s < 2; ++s) {
                int xx = x0 + s * 16 + n;
                f32x4 v = acc[c][rr][s];
                long cloff = (((long)b * CLY + 4 + yy) * CLY + 4 + xx) * 64 + co_l;
                if (MODE == 0) {
                    if (cog == 0) {
                        union { unsigned short us[4]; unsigned long long d; } t;
                        #pragma unroll
                        for (int q4 = 0; q4 < 4; ++q4)
                            t.us[q4] = f2bf(sigmoidf_(v[q4] + bias_a[co_l + q4]));
                        *(unsigned long long*)(ubuf + (((long)b * HW + yy * IMG + xx) * 64 + co_l)) = t.d;
                    } else {
                        union { unsigned short us[4]; unsigned long long d; } hh, t;
                        hh.d = *(const unsigned long long*)(clh + cloff);
                        #pragma unroll
                        for (int q4 = 0; q4 < 4; ++q4) {
                            float rv = sigmoidf_(v[q4] + bias_b[co_l + q4]);
                            t.us[q4] = f2bf(bf2f(hh.us[q4]) * rv);
                        }
                        *(unsigned long long*)(clh2 + cloff) = t.d;
                    }
                } else {
                    union { unsigned short us[4]; unsigned long long d; } uu, hh, t;
                    uu.d = *(const unsigned long long*)(ubuf + (((long)b * HW + yy * IMG + xx) * 64 + co_l));
                    hh.d = *(const unsigned long long*)(clhL + cloff);
                    #pragma unroll
                    for (int q4 = 0; q4 < 4; ++q4) {
                        float o  = tanhf_(v[q4] + bias_a[co_l + q4]);
                        float hv = bf2f(hh.us[q4]);
                        float uv = bf2f(uu.us[q4]);
                        t.us[q4] = f2bf(hv + uv * (o - hv));
                    }
                    *(unsigned long long*)(clhL + cloff) = t.d;
                }
            }
        }
    }
}

// ---------------------------------------------------------------------------
// 1x1 conv: thread = 4 px x 8 co (x read once per octet), NT stores.
// ---------------------------------------------------------------------------
__global__ void conv1x1(const float* __restrict__ x, const float* __restrict__ w,
                        const float* __restrict__ bias, float* __restrict__ out) {
    int i  = blockIdx.x * 256 + threadIdx.x;   // 24*4096*8 = 786,432
    int p4 = i & 4095;
    int oc = (i >> 12) & 7;
    int f  = i >> 15;
    const float4* xb = reinterpret_cast<const float4*>(x + (long)f * 3 * HW);
    float4 x0 = xb[p4];
    float4 x1 = xb[p4 + 4096];
    float4 x2 = xb[p4 + 8192];
    f32x4* ob = (f32x4*)out + ((long)f * 64 << 12) + p4;
    #pragma unroll
    for (int j = 0; j < 8; ++j) {
        int co = oc * 8 + j;
        float w0 = w[co * 3], w1 = w[co * 3 + 1], w2 = w[co * 3 + 2];
        float bv = bias[co];
        f32x4 o;
        o[0] = bv + x0.x * w0 + x1.x * w1 + x2.x * w2;
        o[1] = bv + x0.y * w0 + x1.y * w1 + x2.y * w2;
        o[2] = bv + x0.z * w0 + x1.z * w1 + x2.z * w2;
        o[3] = bv + x0.w * w0 + x1.w * w1 + x2.w * w2;
        __builtin_nontemporal_store(o, ob + ((long)co << 12));
    }
}

// ---------------------------------------------------------------------------
extern "C" void kernel_launch(void* const* d_in, const int* in_sizes, int n_in,
                              void* d_out, int out_size, void* d_ws, size_t ws_size,
                              hipStream_t stream) {
    (void)in_sizes; (void)n_in; (void)out_size; (void)d_ws; (void)ws_size;

    const float* x  = (const float*)d_in[0];
    const float* w1 = (const float*)d_in[4];
    const float* b1 = (const float*)d_in[5];

    float* out = (float*)d_out;

    const long X0_N = 24L * CH * HW;         // 25,165,824 floats (x0 region)
    const long HN   = (long)Bn * CH * HW;    //  4,194,304 floats

    // fp32 NCHW hidden-state OUTPUT slots (written only at the very end)
    float* H[3] = { out + X0_N, out + X0_N + HN, out + X0_N + 2 * HN };

    // scratch carved from the x0 region (overwritten by conv1x1 at the end)
    unsigned short* sc    = (unsigned short*)out;
    unsigned short* ubuf  = sc;                          //  4,194,304 us
    unsigned short* CLH0  = sc + 4194304;                //  CLN each
    unsigned short* CLH1  = CLH0 + CLN;
    unsigned short* CLH2  = CLH1 + CLN;
    unsigned short* clh2  = CLH2 + CLN;                  //  h*r buffer
    unsigned short* clinx = clh2 + CLN;                  //  CLNX (32-ch, L0 x)
    unsigned short* wt    = clinx + CLNX;                //  1,984,512 us
    // end = 27,486,208 us = 13,743,104 f < 25,165,824 f  OK

    const long WT_UR[3] = { 0,      165888, 780288  };
    const long WT_O [3] = { 110592, 575488, 1583104 };

    const int Ks[3]   = { 3, 5, 7 };
    const int C0s[3]  = { CIN, CH, CH };
    const int NCIC[3] = { 3, 4, 4 };

    // zero CLH0..clinx once (halos must stay zero; interiors rewritten)
    hipMemsetAsync(CLH0, 0, (4 * CLN + CLNX) * sizeof(unsigned short), stream);

    // weight transforms (cog-major layout)
    for (int L = 0; L < 3; ++L) {
        const float* wr = (const float*)d_in[6 + 6 * L];
        const float* wu = (const float*)d_in[8 + 6 * L];
        const float* wo = (const float*)d_in[10 + 6 * L];
        int K = Ks[L], C0 = C0s[L], NC = NCIC[L];
        int tot_ur = 2 * K * K * NC * 4 * 64;
        int tot_o  = 1 * K * K * NC * 4 * 64;
        xform_w<<<(tot_ur + 255) / 256, 256, 0, stream>>>(wu, wr, wt + WT_UR[L], K, C0, NC, 2);
        xform_w<<<(tot_o  + 255) / 256, 256, 0, stream>>>(wo, wo, wt + WT_O[L],  K, C0, NC, 1);
    }

    // init CLH[L] from h0 inputs (fp32 NCHW -> bf16 CL)
    unsigned short* CLH[3] = { CLH0, CLH1, CLH2 };
    for (int L = 0; L < 3; ++L)
        build_cl<<<4 * 8 * 64, 256, 0, stream>>>((const float*)d_in[1 + L],
                                                 (long)CH * HW, 64, CLH[L], 8, 64);

    for (int t = 0; t < T; ++t) {
        // L0 input staging (tiny: 3 real channels into 32-stride buffer)
        build_cl<<<4 * 4 * 64, 256, 0, stream>>>(x + (long)t * CIN * HW,
                                                 (long)T * CIN * HW, CIN, clinx, 4, 32);
        {
            const float* br = (const float*)d_in[7];
            const float* bu = (const float*)d_in[9];
            const float* bo = (const float*)d_in[11];
            conv_l0<3, 3, 4, 0, 32><<<dim3(256, 2), 256, 0, stream>>>(
                CLH0, clinx, wt + WT_UR[0], bu, br, ubuf, clh2, nullptr);
            conv_l0<3, 3, 2, 1, 32><<<dim3(512, 1), 256, 0, stream>>>(
                clh2, clinx, wt + WT_O[0], bo, nullptr, ubuf, nullptr, CLH0);
        }
        {
            const float* br = (const float*)d_in[13];
            const float* bu = (const float*)d_in[15];
            const float* bo = (const float*)d_in[17];
            conv_db<5, 0><<<512, 512, 0, stream>>>(
                CLH1, CLH0, wt + WT_UR[1], bu, br, ubuf, clh2, nullptr);
            conv_db<5, 1><<<512, 512, 0, stream>>>(
                clh2, CLH0, wt + WT_O[1], bo, nullptr, ubuf, nullptr, CLH1);
        }
        {
            const float* br = (const float*)d_in[19];
            const float* bu = (const float*)d_in[21];
            const float* bo = (const float*)d_in[23];
            conv_db<7, 0><<<512, 512, 0, stream>>>(
                CLH2, CLH1, wt + WT_UR[2], bu, br, ubuf, clh2, nullptr);
            conv_db<7, 1><<<512, 512, 0, stream>>>(
                clh2, CLH1, wt + WT_O[2], bo, nullptr, ubuf, nullptr, CLH2);
        }
    }

    // final hidden states -> fp32 NCHW output slots
    for (int L = 0; L < 3; ++L)
        unpack_h<<<256, 256, 0, stream>>>(CLH[L], H[L]);

    // x0 projection last — overwrites the scratch region with the real output
    conv1x1<<<786432 / 256, 256, 0, stream>>>(x, w1, b1, out);
}

// Round 20
// 1850.535 us; speedup vs baseline: 1.0829x; 1.0829x over previous
//
#include <hip/hip_runtime.h>
#include <math.h>

// Problem constants
constexpr int Bn  = 4;
constexpr int T   = 6;
constexpr int CIN = 3;
constexpr int CH  = 64;
constexpr int IMG = 128;
constexpr int HW  = IMG * IMG;          // 16384

// Channels-last bf16 buffers, halo 4 each side: [b][136][136][Cstride]
constexpr int CLY = 136;
constexpr long CLN = 4L * CLY * CLY * 64;    // 4,734,976 ushorts (64-ch buffer)
constexpr long CLNX = 4L * CLY * CLY * 32;   // 2,367,488 ushorts (32-ch buffer)

typedef short bf16x8 __attribute__((ext_vector_type(8)));
typedef float f32x4  __attribute__((ext_vector_type(4)));

__device__ __forceinline__ unsigned short f2bf(float f) {
    union { float f; unsigned int u; } v; v.f = f;
    unsigned int u = v.u;
    unsigned int r = (u + 0x7FFFu + ((u >> 16) & 1u)) >> 16;   // RNE
    return (unsigned short)r;
}
__device__ __forceinline__ float bf2f(unsigned short s) {
    union { unsigned int u; float f; } v; v.u = ((unsigned int)s) << 16;
    return v.f;
}
__device__ __forceinline__ float sigmoidf_(float v) { return 1.f / (1.f + __expf(-v)); }
__device__ __forceinline__ float tanhf_(float v)    { return 1.f - 2.f / (1.f + __expf(2.f * v)); }

// ---------------------------------------------------------------------------
// Weight transform: OIHW fp32 -> MFMA A-frag bf16, cog-major frag layout:
//   frag f = ((cog*KK + kyx)*NCIC + cic)*4 + c ; co = c*16+(lane&15),
//   ci_new = cic*32 + (lane>>4)*8 + j ; ci_new<64 -> h, else input.
// ---------------------------------------------------------------------------
__global__ void xform_w(const float* __restrict__ wA, const float* __restrict__ wB,
                        unsigned short* __restrict__ dst,
                        int K, int C0, int NCIC, int NG) {
    int idx   = blockIdx.x * 256 + threadIdx.x;
    int total = NG * K * K * NCIC * 4 * 64;
    if (idx >= total) return;
    int CI   = C0 + 64;
    int KK   = K * K;
    int lane = idx & 63;
    int rest = idx >> 6;
    int c    = rest & 3; rest >>= 2;
    int cic  = rest % NCIC; rest /= NCIC;
    int kyx  = rest % KK;
    int cog  = rest / KK;
    const float* w = cog ? wB : wA;
    int co = c * 16 + (lane & 15);
    union { unsigned short u[8]; uint4 q; } t;
    #pragma unroll
    for (int j = 0; j < 8; ++j) {
        int ci_new = cic * 32 + ((lane >> 4) * 8) + j;
        int ci_o   = (ci_new < 64) ? (C0 + ci_new) : (ci_new - 64);
        bool valid = (ci_new < 64) || (ci_new - 64 < C0);
        float f = valid ? w[((long)co * CI + ci_o) * KK + kyx] : 0.f;
        t.u[j] = f2bf(f);
    }
    *(uint4*)(dst + (long)(idx >> 6) * 8 * 64 + lane * 8) = t.q;
}

// ---------------------------------------------------------------------------
// Build a channels-last bf16 buffer from NCHW fp32 (stride CST channels)
// ---------------------------------------------------------------------------
__global__ void build_cl(const float* __restrict__ src, long bstride, int C0,
                         unsigned short* __restrict__ dst, int NG, int CST) {
    int i    = blockIdx.x * 256 + threadIdx.x;
    int px   = i & 16383;
    int rest = i >> 14;
    int g    = rest % NG;
    int b    = rest / NG;
    int y    = px >> 7, x = px & 127;
    union { unsigned short u[8]; uint4 q; } t;
    #pragma unroll
    for (int j = 0; j < 8; ++j) {
        int ci  = g * 8 + j;
        float f = (ci < C0) ? src[(long)b * bstride + (long)ci * HW + px] : 0.f;
        t.u[j] = f2bf(f);
    }
    long off = (((long)b * CLY + 4 + y) * CLY + 4 + x) * CST + g * 8;
    *(uint4*)(dst + off) = t.q;
}

// ---------------------------------------------------------------------------
// Unpack CLH (bf16 ch-last) -> H fp32 NCHW (final output form)
// ---------------------------------------------------------------------------
__global__ void unpack_h(const unsigned short* __restrict__ clh, float* __restrict__ H) {
    int i  = blockIdx.x * 256 + threadIdx.x;   // 4*16384 threads
    int b  = i >> 14, px = i & 16383;
    int y  = px >> 7, x = px & 127;
    const unsigned short* p = clh + (((long)b * CLY + 4 + y) * CLY + 4 + x) * 64;
    float* Hb = H + (long)b * 64 * HW + px;
    #pragma unroll
    for (int g = 0; g < 8; ++g) {
        union { unsigned short us[8]; uint4 q; } t;
        t.q = *(const uint4*)(p + g * 8);
        #pragma unroll
        for (int j = 0; j < 8; ++j)
            Hb[(long)(g * 8 + j) * HW] = bf2f(t.us[j]);
    }
}

// ---------------------------------------------------------------------------
// L0 conv (K=3, CST=32): weights LDS-staged per kyx, B global (r15 exact).
// ---------------------------------------------------------------------------
template<int K, int NCIC, int S, int MODE, int CST>
__global__ __launch_bounds__(256)
void conv_l0(const unsigned short* __restrict__ clh,
             const unsigned short* __restrict__ clin,
             const unsigned short* __restrict__ wt,
             const float* __restrict__ bias_a,
             const float* __restrict__ bias_b,
             unsigned short* __restrict__ ubuf,
             unsigned short* __restrict__ clh2,
             unsigned short* __restrict__ clhL)
{
    constexpr int HOFF = 4 - K / 2;
    constexpr int KK   = K * K;
    constexpr int NF   = NCIC * 4;
    __shared__ unsigned short alds[2][NF * 512];

    int w    = threadIdx.x >> 6;
    int lane = threadIdx.x & 63;
    int cog  = (MODE == 0) ? blockIdx.y : 0;
    int m    = blockIdx.x;
    int k8   = m & 7;
    int q    = m >> 3;
    int b    = k8 >> 1;
    int y, x0;
    if (S == 4) { y = (k8 & 1) * 64 + (q >> 1) * 4 + w; x0 = (q & 1) * 64; }
    else        { y = (k8 & 1) * 64 + (q >> 2) * 4 + w; x0 = (q & 3) * 32; }
    int n  = lane & 15;
    int kg = lane >> 4;

    f32x4 acc[4][S];
    #pragma unroll
    for (int c = 0; c < 4; ++c)
        #pragma unroll
        for (int s = 0; s < S; ++s)
            acc[c][s] = (f32x4){0.f, 0.f, 0.f, 0.f};

    long rbh = ((long)(b * CLY + HOFF + y) * CLY + HOFF + x0 + n) * 64 + kg * 8;
    long rbi = ((long)(b * CLY + HOFF + y) * CLY + HOFF + x0 + n) * CST + kg * 8;
    const unsigned short* wcog = wt + (long)cog * KK * NF * 512;

    #define STAGEW(bi, kyx_) do {                                              \
        const unsigned short* _src = wcog + (long)(kyx_) * NF * 512;           \
        _Pragma("unroll")                                                      \
        for (int j = 0; j < NCIC; ++j) {                                       \
            int f = j * 4 + w;                                                 \
            __builtin_amdgcn_global_load_lds(                                  \
                (const __attribute__((address_space(1))) void*)(_src + f * 512 + lane * 8), \
                (__attribute__((address_space(3))) void*)(&alds[bi][f * 512]), \
                16, 0, 0);                                                     \
        }                                                                      \
    } while (0)

    STAGEW(0, 0);
    int cur = 0;
    for (int kyx = 0; kyx < KK; ++kyx) {
        if (kyx + 1 < KK) {
            STAGEW(cur ^ 1, kyx + 1);
            asm volatile("s_waitcnt vmcnt(%0)" :: "n"(NCIC) : "memory");
        } else {
            asm volatile("s_waitcnt vmcnt(0)" ::: "memory");
        }
        __builtin_amdgcn_s_barrier();
        asm volatile("" ::: "memory");

        int ky = kyx / K;
        int kx = kyx - ky * K;
        long offh = rbh + (long)(ky * CLY + kx) * 64;
        long offi = rbi + (long)(ky * CLY + kx) * CST;
        #pragma unroll
        for (int cic = 0; cic < NCIC; ++cic) {
            bf16x8 bfr[S], afr[4];
            #pragma unroll
            for (int s = 0; s < S; ++s) {
                if (cic < 2) bfr[s] = *(const bf16x8*)(clh  + offh + s * 16 * 64  + cic * 32);
                else         bfr[s] = *(const bf16x8*)(clin + offi + s * 16 * CST + (cic - 2) * 32);
            }
            #pragma unroll
            for (int c = 0; c < 4; ++c)
                afr[c] = *(const bf16x8*)(&alds[cur][(cic * 4 + c) * 512 + lane * 8]);
            #pragma unroll
            for (int c = 0; c < 4; ++c)
                #pragma unroll
                for (int s = 0; s < S; ++s)
                    acc[c][s] = __builtin_amdgcn_mfma_f32_16x16x32_bf16(afr[c], bfr[s], acc[c][s], 0, 0, 0);
        }
        asm volatile("" ::: "memory");
        __builtin_amdgcn_s_barrier();
        cur ^= 1;
    }
    #undef STAGEW

    #pragma unroll
    for (int coc = 0; coc < 4; ++coc) {
        int co_l = coc * 16 + kg * 4;
        #pragma unroll
        for (int s = 0; s < S; ++s) {
            int x = x0 + s * 16 + n;
            f32x4 v = acc[coc][s];
            long cloff = (((long)b * CLY + 4 + y) * CLY + 4 + x) * 64 + co_l;
            if (MODE == 0) {
                if (cog == 0) {
                    union { unsigned short us[4]; unsigned long long d; } t;
                    #pragma unroll
                    for (int rr = 0; rr < 4; ++rr)
                        t.us[rr] = f2bf(sigmoidf_(v[rr] + bias_a[co_l + rr]));
                    *(unsigned long long*)(ubuf + (((long)b * HW + y * IMG + x) * 64 + co_l)) = t.d;
                } else {
                    union { unsigned short us[4]; unsigned long long d; } hh, t;
                    hh.d = *(const unsigned long long*)(clh + cloff);
                    #pragma unroll
                    for (int rr = 0; rr < 4; ++rr) {
                        float rv = sigmoidf_(v[rr] + bias_b[co_l + rr]);
                        t.us[rr] = f2bf(bf2f(hh.us[rr]) * rv);
                    }
                    *(unsigned long long*)(clh2 + cloff) = t.d;
                }
            } else {
                union { unsigned short us[4]; unsigned long long d; } uu, hh, t;
                uu.d = *(const unsigned long long*)(ubuf + (((long)b * HW + y * IMG + x) * 64 + co_l));
                hh.d = *(const unsigned long long*)(clhL + cloff);
                #pragma unroll
                for (int rr = 0; rr < 4; ++rr) {
                    float o  = tanhf_(v[rr] + bias_a[co_l + rr]);
                    float hv = bf2f(hh.us[rr]);
                    float uv = bf2f(uu.us[rr]);
                    t.us[rr] = f2bf(hv + uv * (o - hv));
                }
                *(unsigned long long*)(clhL + cloff) = t.d;
            }
        }
    }
}

// ---------------------------------------------------------------------------
// K=5/7 conv — r15 exact: r12 geometry + depth-4 A-prefetch.
//   Block = 8 waves (512 thr) = 4 rows x 32 px x 64 co (x2 gates MODE0).
//   Wave tile = 2 rows x 32 px x (MODE0: 32 co | MODE1: 16 co).
//   B tile in LDS [cg][row][px]x16B, SUBTP-padded (stride ≡ 0 mod 128B, 0
//   conflicts); tile[2] dbuf, stage(p+1) before compute(p), counted vmcnt.
//   Flattened tap loop loads A(t+4) before the MFMAs of A(t).
//   XCD swizzle: k8=blockIdx.x&7 -> (b=k8>>1, 64-row half k8&1).
// ---------------------------------------------------------------------------
template<int K, int MODE>
__global__ __launch_bounds__(512, 4)
void conv_db(const unsigned short* __restrict__ clh,
             const unsigned short* __restrict__ clin,
             const unsigned short* __restrict__ wt,
             const float* __restrict__ bias_a,
             const float* __restrict__ bias_b,
             unsigned short* __restrict__ ubuf,
             unsigned short* __restrict__ clh2,
             unsigned short* __restrict__ clhL)
{
    constexpr int HOFF = 4 - K / 2;
    constexpr int KK   = K * K;
    constexpr int ROWS = K + 3;
    constexpr int PXT  = 31 + K;
    constexpr int SUBT = ROWS * PXT;
    constexpr int SUBTP = (SUBT + 7) & ~7;      // stride ≡ 0 mod 128B
    constexpr int NCHUNK = 4 * SUBTP;
    constexpr int NGRP = NCHUNK / 64;
    constexpr int VCNT = NGRP / 8;
    constexpr int NCW = (MODE == 0) ? 2 : 1;
    constexpr int D   = 4;                      // A-prefetch depth (taps)

    __shared__ __align__(16) unsigned char tile[2][NCHUNK * 16];

    int tid  = threadIdx.x;
    int w    = tid >> 6;
    int lane = tid & 63;
    int cog  = (MODE == 0) ? (w >> 2) : 0;
    int cb   = (MODE == 0) ? ((w >> 1) & 1) * 2 : (w >> 1);
    int rp   = w & 1;
    int m    = blockIdx.x;
    int k8   = m & 7;
    int t8   = m >> 3;
    int b    = k8 >> 1;
    int y0   = (k8 & 1) * 64 + (t8 >> 2) * 4;
    int x0   = (t8 & 3) * 32;
    int n    = lane & 15;
    int kg   = lane >> 4;

    f32x4 acc[NCW][2][2];
    #pragma unroll
    for (int c = 0; c < NCW; ++c)
        #pragma unroll
        for (int rr = 0; rr < 2; ++rr)
            #pragma unroll
            for (int s = 0; s < 2; ++s)
                acc[c][rr][s] = (f32x4){0.f, 0.f, 0.f, 0.f};

    const unsigned short* wbase = wt + (long)cog * KK * 16 * 512;

    #define STAGE(bi, ph_) do {                                                \
        const unsigned short* sp_ = ((ph_) < 2) ? clh : clin;                  \
        int half_ = ((ph_) & 1) * 32;                                          \
        _Pragma("unroll 1")                                                    \
        for (int g = w; g < NGRP; g += 8) {                                    \
            int c_  = g * 64 + lane;                                           \
            int cg  = c_ / SUBTP;                                              \
            int rem = c_ - cg * SUBTP;                                         \
            int r   = rem / PXT;                                               \
            int px  = rem - r * PXT;                                           \
            const unsigned short* src_ = sp_ +                                 \
                (((long)(b * CLY + HOFF + y0 + r)) * CLY + (HOFF + x0 + px)) * 64 \
                + half_ + cg * 8;                                              \
            __builtin_amdgcn_global_load_lds(                                  \
                (const __attribute__((address_space(1))) void*)src_,           \
                (__attribute__((address_space(3))) void*)(&tile[bi][g * 64 * 16]), \
                16, 0, 0);                                                     \
        }                                                                      \
    } while (0)

    int cur = 0;
    STAGE(0, 0);
    #pragma unroll 1
    for (int ph = 0; ph < 4; ++ph) {
        if (ph < 3) {
            STAGE(cur ^ 1, ph + 1);
            asm volatile("s_waitcnt vmcnt(%0)" :: "n"(VCNT) : "memory");
        } else {
            asm volatile("s_waitcnt vmcnt(0)" ::: "memory");
        }
        __builtin_amdgcn_s_barrier();
        asm volatile("" ::: "memory");

        const unsigned char* tb = tile[cur];
        // A-frag base for this phase; per-tap stride = 16 frags * 512 us
        const unsigned short* wph = wbase + (long)(4 * ph + cb) * 512 + lane * 8;

        // prime prefetch pipeline: taps 0..D-1
        bf16x8 apre[D][NCW];
        #pragma unroll
        for (int tt = 0; tt < D; ++tt)
            #pragma unroll
            for (int c = 0; c < NCW; ++c)
                apre[tt][c] = *(const bf16x8*)(wph + (long)tt * 8192 + c * 512);

        #pragma unroll
        for (int t = 0; t < KK; ++t) {
            constexpr int PXB = PXT * 16;
            int slot = t % D;                    // static after full unroll
            bf16x8 aC[NCW];
            #pragma unroll
            for (int c = 0; c < NCW; ++c) aC[c] = apre[slot][c];
            if (t + D < KK) {
                #pragma unroll
                for (int c = 0; c < NCW; ++c)
                    apre[slot][c] = *(const bf16x8*)(wph + (long)(t + D) * 8192 + c * 512);
            }
            int ky = t / K, kx = t - (t / K) * K;
            const unsigned char* row0 = tb + (kg * SUBTP + (rp * 2 + 0 + ky) * PXT) * 16;
            const unsigned char* row1 = row0 + PXB;
            bf16x8 bv[2][2];
            #pragma unroll
            for (int s = 0; s < 2; ++s) {
                bv[0][s] = *(const bf16x8*)(row0 + (kx + s * 16 + n) * 16);
                bv[1][s] = *(const bf16x8*)(row1 + (kx + s * 16 + n) * 16);
            }
            #pragma unroll
            for (int c = 0; c < NCW; ++c)
                #pragma unroll
                for (int rr = 0; rr < 2; ++rr)
                    #pragma unroll
                    for (int s = 0; s < 2; ++s)
                        acc[c][rr][s] = __builtin_amdgcn_mfma_f32_16x16x32_bf16(aC[c], bv[rr][s], acc[c][rr][s], 0, 0, 0);
        }
        asm volatile("" ::: "memory");
        __builtin_amdgcn_s_barrier();
        cur ^= 1;
    }
    #undef STAGE

    // ---- epilogue ----
    #pragma unroll
    for (int c = 0; c < NCW; ++c) {
        int co_l = (cb + c) * 16 + kg * 4;
        #pragma unroll
        for (int rr = 0; rr < 2; ++rr) {
            int yy = y0 + rp * 2 + rr;
            #pragma unroll
            for (int s = 0; s < 2; ++s) {
                int xx = x0 + s * 16 + n;
                f32x4 v = acc[c][rr][s];
                long cloff = (((long)b * CLY + 4 + yy) * CLY + 4 + xx) * 64 + co_l;
                if (MODE == 0) {
                    if (cog == 0) {
                        union { unsigned short us[4]; unsigned long long d; } t;
                        #pragma unroll
                        for (int q4 = 0; q4 < 4; ++q4)
                            t.us[q4] = f2bf(sigmoidf_(v[q4] + bias_a[co_l + q4]));
                        *(unsigned long long*)(ubuf + (((long)b * HW + yy * IMG + xx) * 64 + co_l)) = t.d;
                    } else {
                        union { unsigned short us[4]; unsigned long long d; } hh, t;
                        hh.d = *(const unsigned long long*)(clh + cloff);
                        #pragma unroll
                        for (int q4 = 0; q4 < 4; ++q4) {
                            float rv = sigmoidf_(v[q4] + bias_b[co_l + q4]);
                            t.us[q4] = f2bf(bf2f(hh.us[q4]) * rv);
                        }
                        *(unsigned long long*)(clh2 + cloff) = t.d;
                    }
                } else {
                    union { unsigned short us[4]; unsigned long long d; } uu, hh, t;
                    uu.d = *(const unsigned long long*)(ubuf + (((long)b * HW + yy * IMG + xx) * 64 + co_l));
                    hh.d = *(const unsigned long long*)(clhL + cloff);
                    #pragma unroll
                    for (int q4 = 0; q4 < 4; ++q4) {
                        float o  = tanhf_(v[q4] + bias_a[co_l + q4]);
                        float hv = bf2f(hh.us[q4]);
                        float uv = bf2f(uu.us[q4]);
                        t.us[q4] = f2bf(hv + uv * (o - hv));
                    }
                    *(unsigned long long*)(clhL + cloff) = t.d;
                }
            }
        }
    }
}

// ---------------------------------------------------------------------------
// 1x1 conv: thread = 4 px x 8 co (x read once per octet), NT stores.
// ---------------------------------------------------------------------------
__global__ void conv1x1(const float* __restrict__ x, const float* __restrict__ w,
                        const float* __restrict__ bias, float* __restrict__ out) {
    int i  = blockIdx.x * 256 + threadIdx.x;   // 24*4096*8 = 786,432
    int p4 = i & 4095;
    int oc = (i >> 12) & 7;
    int f  = i >> 15;
    const float4* xb = reinterpret_cast<const float4*>(x + (long)f * 3 * HW);
    float4 x0 = xb[p4];
    float4 x1 = xb[p4 + 4096];
    float4 x2 = xb[p4 + 8192];
    f32x4* ob = (f32x4*)out + ((long)f * 64 << 12) + p4;
    #pragma unroll
    for (int j = 0; j < 8; ++j) {
        int co = oc * 8 + j;
        float w0 = w[co * 3], w1 = w[co * 3 + 1], w2 = w[co * 3 + 2];
        float bv = bias[co];
        f32x4 o;
        o[0] = bv + x0.x * w0 + x1.x * w1 + x2.x * w2;
        o[1] = bv + x0.y * w0 + x1.y * w1 + x2.y * w2;
        o[2] = bv + x0.z * w0 + x1.z * w1 + x2.z * w2;
        o[3] = bv + x0.w * w0 + x1.w * w1 + x2.w * w2;
        __builtin_nontemporal_store(o, ob + ((long)co << 12));
    }
}

// ---------------------------------------------------------------------------
extern "C" void kernel_launch(void* const* d_in, const int* in_sizes, int n_in,
                              void* d_out, int out_size, void* d_ws, size_t ws_size,
                              hipStream_t stream) {
    (void)in_sizes; (void)n_in; (void)out_size; (void)d_ws; (void)ws_size;

    const float* x  = (const float*)d_in[0];
    const float* w1 = (const float*)d_in[4];
    const float* b1 = (const float*)d_in[5];

    float* out = (float*)d_out;

    const long X0_N = 24L * CH * HW;         // 25,165,824 floats (x0 region)
    const long HN   = (long)Bn * CH * HW;    //  4,194,304 floats

    // fp32 NCHW hidden-state OUTPUT slots (written only at the very end)
    float* H[3] = { out + X0_N, out + X0_N + HN, out + X0_N + 2 * HN };

    // scratch carved from the x0 region (overwritten by conv1x1 at the end)
    unsigned short* sc    = (unsigned short*)out;
    unsigned short* ubuf  = sc;                          //  4,194,304 us
    unsigned short* CLH0  = sc + 4194304;                //  CLN each
    unsigned short* CLH1  = CLH0 + CLN;
    unsigned short* CLH2  = CLH1 + CLN;
    unsigned short* clh2  = CLH2 + CLN;                  //  h*r buffer
    unsigned short* clinx = clh2 + CLN;                  //  CLNX (32-ch, L0 x)
    unsigned short* wt    = clinx + CLNX;                //  1,984,512 us
    // end = 27,486,208 us = 13,743,104 f < 25,165,824 f  OK

    const long WT_UR[3] = { 0,      165888, 780288  };
    const long WT_O [3] = { 110592, 575488, 1583104 };

    const int Ks[3]   = { 3, 5, 7 };
    const int C0s[3]  = { CIN, CH, CH };
    const int NCIC[3] = { 3, 4, 4 };

    // zero CLH0..clinx once (halos must stay zero; interiors rewritten)
    hipMemsetAsync(CLH0, 0, (4 * CLN + CLNX) * sizeof(unsigned short), stream);

    // weight transforms (cog-major layout)
    for (int L = 0; L < 3; ++L) {
        const float* wr = (const float*)d_in[6 + 6 * L];
        const float* wu = (const float*)d_in[8 + 6 * L];
        const float* wo = (const float*)d_in[10 + 6 * L];
        int K = Ks[L], C0 = C0s[L], NC = NCIC[L];
        int tot_ur = 2 * K * K * NC * 4 * 64;
        int tot_o  = 1 * K * K * NC * 4 * 64;
        xform_w<<<(tot_ur + 255) / 256, 256, 0, stream>>>(wu, wr, wt + WT_UR[L], K, C0, NC, 2);
        xform_w<<<(tot_o  + 255) / 256, 256, 0, stream>>>(wo, wo, wt + WT_O[L],  K, C0, NC, 1);
    }

    // init CLH[L] from h0 inputs (fp32 NCHW -> bf16 CL)
    unsigned short* CLH[3] = { CLH0, CLH1, CLH2 };
    for (int L = 0; L < 3; ++L)
        build_cl<<<4 * 8 * 64, 256, 0, stream>>>((const float*)d_in[1 + L],
                                                 (long)CH * HW, 64, CLH[L], 8, 64);

    for (int t = 0; t < T; ++t) {
        // L0 input staging (tiny: 3 real channels into 32-stride buffer)
        build_cl<<<4 * 4 * 64, 256, 0, stream>>>(x + (long)t * CIN * HW,
                                                 (long)T * CIN * HW, CIN, clinx, 4, 32);
        {
            const float* br = (const float*)d_in[7];
            const float* bu = (const float*)d_in[9];
            const float* bo = (const float*)d_in[11];
            conv_l0<3, 3, 4, 0, 32><<<dim3(256, 2), 256, 0, stream>>>(
                CLH0, clinx, wt + WT_UR[0], bu, br, ubuf, clh2, nullptr);
            conv_l0<3, 3, 2, 1, 32><<<dim3(512, 1), 256, 0, stream>>>(
                clh2, clinx, wt + WT_O[0], bo, nullptr, ubuf, nullptr, CLH0);
        }
        {
            const float* br = (const float*)d_in[13];
            const float* bu = (const float*)d_in[15];
            const float* bo = (const float*)d_in[17];
            conv_db<5, 0><<<512, 512, 0, stream>>>(
                CLH1, CLH0, wt + WT_UR[1], bu, br, ubuf, clh2, nullptr);
            conv_db<5, 1><<<512, 512, 0, stream>>>(
                clh2, CLH0, wt + WT_O[1], bo, nullptr, ubuf, nullptr, CLH1);
        }
        {
            const float* br = (const float*)d_in[19];
            const float* bu = (const float*)d_in[21];
            const float* bo = (const float*)d_in[23];
            conv_db<7, 0><<<512, 512, 0, stream>>>(
                CLH2, CLH1, wt + WT_UR[2], bu, br, ubuf, clh2, nullptr);
            conv_db<7, 1><<<512, 512, 0, stream>>>(
                clh2, CLH1, wt + WT_O[2], bo, nullptr, ubuf, nullptr, CLH2);
        }
    }

    // final hidden states -> fp32 NCHW output slots
    for (int L = 0; L < 3; ++L)
        unpack_h<<<256, 256, 0, stream>>>(CLH[L], H[L]);

    // x0 projection last — overwrites the scratch region with the real output
    conv1x1<<<786432 / 256, 256, 0, stream>>>(x, w1, b1, out);
}

// Round 21
// 1842.351 us; speedup vs baseline: 1.0877x; 1.0044x over previous
//
#include <hip/hip_runtime.h>
#include <math.h>

// Problem constants
constexpr int Bn  = 4;
constexpr int T   = 6;
constexpr int CIN = 3;
constexpr int CH  = 64;
constexpr int IMG = 128;
constexpr int HW  = IMG * IMG;          // 16384

// Channels-last bf16 buffers, halo 4 each side: [b][136][136][Cstride]
constexpr int CLY = 136;
constexpr long CLN = 4L * CLY * CLY * 64;    // 4,734,976 ushorts (64-ch buffer)
constexpr long CLNX = 4L * CLY * CLY * 32;   // 2,367,488 ushorts (32-ch buffer)

typedef short bf16x8 __attribute__((ext_vector_type(8)));
typedef float f32x4  __attribute__((ext_vector_type(4)));

__device__ __forceinline__ unsigned short f2bf(float f) {
    union { float f; unsigned int u; } v; v.f = f;
    unsigned int u = v.u;
    unsigned int r = (u + 0x7FFFu + ((u >> 16) & 1u)) >> 16;   // RNE
    return (unsigned short)r;
}
__device__ __forceinline__ float bf2f(unsigned short s) {
    union { unsigned int u; float f; } v; v.u = ((unsigned int)s) << 16;
    return v.f;
}
__device__ __forceinline__ float sigmoidf_(float v) { return 1.f / (1.f + __expf(-v)); }
__device__ __forceinline__ float tanhf_(float v)    { return 1.f - 2.f / (1.f + __expf(2.f * v)); }

// ---------------------------------------------------------------------------
// Weight transform: OIHW fp32 -> MFMA A-frag bf16, cog-major frag layout:
//   frag f = ((cog*KK + kyx)*NCIC + cic)*4 + c ; co = c*16+(lane&15),
//   ci_new = cic*32 + (lane>>4)*8 + j ; ci_new<64 -> h, else input.
// ---------------------------------------------------------------------------
__global__ void xform_w(const float* __restrict__ wA, const float* __restrict__ wB,
                        unsigned short* __restrict__ dst,
                        int K, int C0, int NCIC, int NG) {
    int idx   = blockIdx.x * 256 + threadIdx.x;
    int total = NG * K * K * NCIC * 4 * 64;
    if (idx >= total) return;
    int CI   = C0 + 64;
    int KK   = K * K;
    int lane = idx & 63;
    int rest = idx >> 6;
    int c    = rest & 3; rest >>= 2;
    int cic  = rest % NCIC; rest /= NCIC;
    int kyx  = rest % KK;
    int cog  = rest / KK;
    const float* w = cog ? wB : wA;
    int co = c * 16 + (lane & 15);
    union { unsigned short u[8]; uint4 q; } t;
    #pragma unroll
    for (int j = 0; j < 8; ++j) {
        int ci_new = cic * 32 + ((lane >> 4) * 8) + j;
        int ci_o   = (ci_new < 64) ? (C0 + ci_new) : (ci_new - 64);
        bool valid = (ci_new < 64) || (ci_new - 64 < C0);
        float f = valid ? w[((long)co * CI + ci_o) * KK + kyx] : 0.f;
        t.u[j] = f2bf(f);
    }
    *(uint4*)(dst + (long)(idx >> 6) * 8 * 64 + lane * 8) = t.q;
}

// ---------------------------------------------------------------------------
// Build a channels-last bf16 buffer from NCHW fp32 (stride CST channels)
// ---------------------------------------------------------------------------
__global__ void build_cl(const float* __restrict__ src, long bstride, int C0,
                         unsigned short* __restrict__ dst, int NG, int CST) {
    int i    = blockIdx.x * 256 + threadIdx.x;
    int px   = i & 16383;
    int rest = i >> 14;
    int g    = rest % NG;
    int b    = rest / NG;
    int y    = px >> 7, x = px & 127;
    union { unsigned short u[8]; uint4 q; } t;
    #pragma unroll
    for (int j = 0; j < 8; ++j) {
        int ci  = g * 8 + j;
        float f = (ci < C0) ? src[(long)b * bstride + (long)ci * HW + px] : 0.f;
        t.u[j] = f2bf(f);
    }
    long off = (((long)b * CLY + 4 + y) * CLY + 4 + x) * CST + g * 8;
    *(uint4*)(dst + off) = t.q;
}

// ---------------------------------------------------------------------------
// Unpack CLH (bf16 ch-last) -> H fp32 NCHW (final output form)
// ---------------------------------------------------------------------------
__global__ void unpack_h(const unsigned short* __restrict__ clh, float* __restrict__ H) {
    int i  = blockIdx.x * 256 + threadIdx.x;   // 4*16384 threads
    int b  = i >> 14, px = i & 16383;
    int y  = px >> 7, x = px & 127;
    const unsigned short* p = clh + (((long)b * CLY + 4 + y) * CLY + 4 + x) * 64;
    float* Hb = H + (long)b * 64 * HW + px;
    #pragma unroll
    for (int g = 0; g < 8; ++g) {
        union { unsigned short us[8]; uint4 q; } t;
        t.q = *(const uint4*)(p + g * 8);
        #pragma unroll
        for (int j = 0; j < 8; ++j)
            Hb[(long)(g * 8 + j) * HW] = bf2f(t.us[j]);
    }
}

// ---------------------------------------------------------------------------
// L0 conv (K=3, CST=32): weights LDS-staged per kyx, B global (r15 exact).
// ---------------------------------------------------------------------------
template<int K, int NCIC, int S, int MODE, int CST>
__global__ __launch_bounds__(256)
void conv_l0(const unsigned short* __restrict__ clh,
             const unsigned short* __restrict__ clin,
             const unsigned short* __restrict__ wt,
             const float* __restrict__ bias_a,
             const float* __restrict__ bias_b,
             unsigned short* __restrict__ ubuf,
             unsigned short* __restrict__ clh2,
             unsigned short* __restrict__ clhL)
{
    constexpr int HOFF = 4 - K / 2;
    constexpr int KK   = K * K;
    constexpr int NF   = NCIC * 4;
    __shared__ unsigned short alds[2][NF * 512];

    int w    = threadIdx.x >> 6;
    int lane = threadIdx.x & 63;
    int cog  = (MODE == 0) ? blockIdx.y : 0;
    int m    = blockIdx.x;
    int k8   = m & 7;
    int q    = m >> 3;
    int b    = k8 >> 1;
    int y, x0;
    if (S == 4) { y = (k8 & 1) * 64 + (q >> 1) * 4 + w; x0 = (q & 1) * 64; }
    else        { y = (k8 & 1) * 64 + (q >> 2) * 4 + w; x0 = (q & 3) * 32; }
    int n  = lane & 15;
    int kg = lane >> 4;

    f32x4 acc[4][S];
    #pragma unroll
    for (int c = 0; c < 4; ++c)
        #pragma unroll
        for (int s = 0; s < S; ++s)
            acc[c][s] = (f32x4){0.f, 0.f, 0.f, 0.f};

    long rbh = ((long)(b * CLY + HOFF + y) * CLY + HOFF + x0 + n) * 64 + kg * 8;
    long rbi = ((long)(b * CLY + HOFF + y) * CLY + HOFF + x0 + n) * CST + kg * 8;
    const unsigned short* wcog = wt + (long)cog * KK * NF * 512;

    #define STAGEW(bi, kyx_) do {                                              \
        const unsigned short* _src = wcog + (long)(kyx_) * NF * 512;           \
        _Pragma("unroll")                                                      \
        for (int j = 0; j < NCIC; ++j) {                                       \
            int f = j * 4 + w;                                                 \
            __builtin_amdgcn_global_load_lds(                                  \
                (const __attribute__((address_space(1))) void*)(_src + f * 512 + lane * 8), \
                (__attribute__((address_space(3))) void*)(&alds[bi][f * 512]), \
                16, 0, 0);                                                     \
        }                                                                      \
    } while (0)

    STAGEW(0, 0);
    int cur = 0;
    for (int kyx = 0; kyx < KK; ++kyx) {
        if (kyx + 1 < KK) {
            STAGEW(cur ^ 1, kyx + 1);
            asm volatile("s_waitcnt vmcnt(%0)" :: "n"(NCIC) : "memory");
        } else {
            asm volatile("s_waitcnt vmcnt(0)" ::: "memory");
        }
        __builtin_amdgcn_s_barrier();
        asm volatile("" ::: "memory");

        int ky = kyx / K;
        int kx = kyx - ky * K;
        long offh = rbh + (long)(ky * CLY + kx) * 64;
        long offi = rbi + (long)(ky * CLY + kx) * CST;
        #pragma unroll
        for (int cic = 0; cic < NCIC; ++cic) {
            bf16x8 bfr[S], afr[4];
            #pragma unroll
            for (int s = 0; s < S; ++s) {
                if (cic < 2) bfr[s] = *(const bf16x8*)(clh  + offh + s * 16 * 64  + cic * 32);
                else         bfr[s] = *(const bf16x8*)(clin + offi + s * 16 * CST + (cic - 2) * 32);
            }
            #pragma unroll
            for (int c = 0; c < 4; ++c)
                afr[c] = *(const bf16x8*)(&alds[cur][(cic * 4 + c) * 512 + lane * 8]);
            #pragma unroll
            for (int c = 0; c < 4; ++c)
                #pragma unroll
                for (int s = 0; s < S; ++s)
                    acc[c][s] = __builtin_amdgcn_mfma_f32_16x16x32_bf16(afr[c], bfr[s], acc[c][s], 0, 0, 0);
        }
        asm volatile("" ::: "memory");
        __builtin_amdgcn_s_barrier();
        cur ^= 1;
    }
    #undef STAGEW

    #pragma unroll
    for (int coc = 0; coc < 4; ++coc) {
        int co_l = coc * 16 + kg * 4;
        #pragma unroll
        for (int s = 0; s < S; ++s) {
            int x = x0 + s * 16 + n;
            f32x4 v = acc[coc][s];
            long cloff = (((long)b * CLY + 4 + y) * CLY + 4 + x) * 64 + co_l;
            if (MODE == 0) {
                if (cog == 0) {
                    union { unsigned short us[4]; unsigned long long d; } t;
                    #pragma unroll
                    for (int rr = 0; rr < 4; ++rr)
                        t.us[rr] = f2bf(sigmoidf_(v[rr] + bias_a[co_l + rr]));
                    *(unsigned long long*)(ubuf + (((long)b * HW + y * IMG + x) * 64 + co_l)) = t.d;
                } else {
                    union { unsigned short us[4]; unsigned long long d; } hh, t;
                    hh.d = *(const unsigned long long*)(clh + cloff);
                    #pragma unroll
                    for (int rr = 0; rr < 4; ++rr) {
                        float rv = sigmoidf_(v[rr] + bias_b[co_l + rr]);
                        t.us[rr] = f2bf(bf2f(hh.us[rr]) * rv);
                    }
                    *(unsigned long long*)(clh2 + cloff) = t.d;
                }
            } else {
                union { unsigned short us[4]; unsigned long long d; } uu, hh, t;
                uu.d = *(const unsigned long long*)(ubuf + (((long)b * HW + y * IMG + x) * 64 + co_l));
                hh.d = *(const unsigned long long*)(clhL + cloff);
                #pragma unroll
                for (int rr = 0; rr < 4; ++rr) {
                    float o  = tanhf_(v[rr] + bias_a[co_l + rr]);
                    float hv = bf2f(hh.us[rr]);
                    float uv = bf2f(uu.us[rr]);
                    t.us[rr] = f2bf(hv + uv * (o - hv));
                }
                *(unsigned long long*)(clhL + cloff) = t.d;
            }
        }
    }
}

// ---------------------------------------------------------------------------
// K=5/7 conv — r15 structure + hoisted stage-address computation:
//   the per-g {cg,r,px} division chains are phase-invariant, so they are
//   computed ONCE into registers (NGI<=3 entries, compile-time indexed)
//   instead of once per phase (4x). Everything else r18-identical.
// ---------------------------------------------------------------------------
template<int K, int MODE>
__global__ __launch_bounds__(512, 4)
void conv_db(const unsigned short* __restrict__ clh,
             const unsigned short* __restrict__ clin,
             const unsigned short* __restrict__ wt,
             const float* __restrict__ bias_a,
             const float* __restrict__ bias_b,
             unsigned short* __restrict__ ubuf,
             unsigned short* __restrict__ clh2,
             unsigned short* __restrict__ clhL)
{
    constexpr int HOFF = 4 - K / 2;
    constexpr int KK   = K * K;
    constexpr int ROWS = K + 3;
    constexpr int PXT  = 31 + K;
    constexpr int SUBT = ROWS * PXT;
    constexpr int SUBTP = (SUBT + 7) & ~7;      // stride ≡ 0 mod 128B
    constexpr int NCHUNK = 4 * SUBTP;
    constexpr int NGRP = NCHUNK / 64;
    constexpr int VCNT = NGRP / 8;
    constexpr int NCW = (MODE == 0) ? 2 : 1;
    constexpr int D   = 4;                      // A-prefetch depth (taps)
    constexpr int NGI = (NGRP + 7) / 8;         // stage iters per wave (<=3)

    __shared__ __align__(16) unsigned char tile[2][NCHUNK * 16];

    int tid  = threadIdx.x;
    int w    = tid >> 6;
    int lane = tid & 63;
    int cog  = (MODE == 0) ? (w >> 2) : 0;
    int cb   = (MODE == 0) ? ((w >> 1) & 1) * 2 : (w >> 1);
    int rp   = w & 1;
    int m    = blockIdx.x;
    int k8   = m & 7;
    int t8   = m >> 3;
    int b    = k8 >> 1;
    int y0   = (k8 & 1) * 64 + (t8 >> 2) * 4;
    int x0   = (t8 & 3) * 32;
    int n    = lane & 15;
    int kg   = lane >> 4;

    f32x4 acc[NCW][2][2];
    #pragma unroll
    for (int c = 0; c < NCW; ++c)
        #pragma unroll
        for (int rr = 0; rr < 2; ++rr)
            #pragma unroll
            for (int s = 0; s < 2; ++s)
                acc[c][rr][s] = (f32x4){0.f, 0.f, 0.f, 0.f};

    const unsigned short* wbase = wt + (long)cog * KK * 16 * 512;

    // ---- hoisted stage addresses (phase-invariant): per g-iteration the
    // source pixel/channel-group offset and LDS dest byte offset ----
    long goff[NGI];
    int  gdst[NGI];
    #pragma unroll
    for (int gi = 0; gi < NGI; ++gi) {
        int g = w + gi * 8;
        if (g < NGRP) {
            int c_  = g * 64 + lane;
            int cg  = c_ / SUBTP;
            int rem = c_ - cg * SUBTP;
            int r   = rem / PXT;
            int px  = rem - r * PXT;
            goff[gi] = (((long)(b * CLY + HOFF + y0 + r)) * CLY + (HOFF + x0 + px)) * 64 + cg * 8;
            gdst[gi] = g * 64 * 16;
        } else {
            goff[gi] = 0;
            gdst[gi] = -1;
        }
    }

    #define STAGE(bi, ph_) do {                                                \
        const unsigned short* sp_ = ((ph_) < 2) ? clh : clin;                  \
        int half_ = ((ph_) & 1) * 32;                                          \
        _Pragma("unroll")                                                      \
        for (int gi = 0; gi < NGI; ++gi) {                                     \
            if (gdst[gi] >= 0) {                                               \
                __builtin_amdgcn_global_load_lds(                              \
                    (const __attribute__((address_space(1))) void*)(sp_ + goff[gi] + half_), \
                    (__attribute__((address_space(3))) void*)(&tile[bi][gdst[gi]]), \
                    16, 0, 0);                                                 \
            }                                                                  \
        }                                                                      \
    } while (0)

    int cur = 0;
    STAGE(0, 0);
    #pragma unroll 1
    for (int ph = 0; ph < 4; ++ph) {
        if (ph < 3) {
            STAGE(cur ^ 1, ph + 1);
            asm volatile("s_waitcnt vmcnt(%0)" :: "n"(VCNT) : "memory");
        } else {
            asm volatile("s_waitcnt vmcnt(0)" ::: "memory");
        }
        __builtin_amdgcn_s_barrier();
        asm volatile("" ::: "memory");

        const unsigned char* tb = tile[cur];
        // A-frag base for this phase; per-tap stride = 16 frags * 512 us
        const unsigned short* wph = wbase + (long)(4 * ph + cb) * 512 + lane * 8;

        // prime prefetch pipeline: taps 0..D-1
        bf16x8 apre[D][NCW];
        #pragma unroll
        for (int tt = 0; tt < D; ++tt)
            #pragma unroll
            for (int c = 0; c < NCW; ++c)
                apre[tt][c] = *(const bf16x8*)(wph + (long)tt * 8192 + c * 512);

        #pragma unroll
        for (int t = 0; t < KK; ++t) {
            constexpr int PXB = PXT * 16;
            int slot = t % D;                    // static after full unroll
            bf16x8 aC[NCW];
            #pragma unroll
            for (int c = 0; c < NCW; ++c) aC[c] = apre[slot][c];
            if (t + D < KK) {
                #pragma unroll
                for (int c = 0; c < NCW; ++c)
                    apre[slot][c] = *(const bf16x8*)(wph + (long)(t + D) * 8192 + c * 512);
            }
            int ky = t / K, kx = t - (t / K) * K;
            const unsigned char* row0 = tb + (kg * SUBTP + (rp * 2 + 0 + ky) * PXT) * 16;
            const unsigned char* row1 = row0 + PXB;
            bf16x8 bv[2][2];
            #pragma unroll
            for (int s = 0; s < 2; ++s) {
                bv[0][s] = *(const bf16x8*)(row0 + (kx + s * 16 + n) * 16);
                bv[1][s] = *(const bf16x8*)(row1 + (kx + s * 16 + n) * 16);
            }
            #pragma unroll
            for (int c = 0; c < NCW; ++c)
                #pragma unroll
                for (int rr = 0; rr < 2; ++rr)
                    #pragma unroll
                    for (int s = 0; s < 2; ++s)
                        acc[c][rr][s] = __builtin_amdgcn_mfma_f32_16x16x32_bf16(aC[c], bv[rr][s], acc[c][rr][s], 0, 0, 0);
        }
        asm volatile("" ::: "memory");
        __builtin_amdgcn_s_barrier();
        cur ^= 1;
    }
    #undef STAGE

    // ---- epilogue ----
    #pragma unroll
    for (int c = 0; c < NCW; ++c) {
        int co_l = (cb + c) * 16 + kg * 4;
        #pragma unroll
        for (int rr = 0; rr < 2; ++rr) {
            int yy = y0 + rp * 2 + rr;
            #pragma unroll
            for (int s = 0; s < 2; ++s) {
                int xx = x0 + s * 16 + n;
                f32x4 v = acc[c][rr][s];
                long cloff = (((long)b * CLY + 4 + yy) * CLY + 4 + xx) * 64 + co_l;
                if (MODE == 0) {
                    if (cog == 0) {
                        union { unsigned short us[4]; unsigned long long d; } t;
                        #pragma unroll
                        for (int q4 = 0; q4 < 4; ++q4)
                            t.us[q4] = f2bf(sigmoidf_(v[q4] + bias_a[co_l + q4]));
                        *(unsigned long long*)(ubuf + (((long)b * HW + yy * IMG + xx) * 64 + co_l)) = t.d;
                    } else {
                        union { unsigned short us[4]; unsigned long long d; } hh, t;
                        hh.d = *(const unsigned long long*)(clh + cloff);
                        #pragma unroll
                        for (int q4 = 0; q4 < 4; ++q4) {
                            float rv = sigmoidf_(v[q4] + bias_b[co_l + q4]);
                            t.us[q4] = f2bf(bf2f(hh.us[q4]) * rv);
                        }
                        *(unsigned long long*)(clh2 + cloff) = t.d;
                    }
                } else {
                    union { unsigned short us[4]; unsigned long long d; } uu, hh, t;
                    uu.d = *(const unsigned long long*)(ubuf + (((long)b * HW + yy * IMG + xx) * 64 + co_l));
                    hh.d = *(const unsigned long long*)(clhL + cloff);
                    #pragma unroll
                    for (int q4 = 0; q4 < 4; ++q4) {
                        float o  = tanhf_(v[q4] + bias_a[co_l + q4]);
                        float hv = bf2f(hh.us[q4]);
                        float uv = bf2f(uu.us[q4]);
                        t.us[q4] = f2bf(hv + uv * (o - hv));
                    }
                    *(unsigned long long*)(clhL + cloff) = t.d;
                }
            }
        }
    }
}

// ---------------------------------------------------------------------------
// 1x1 conv: thread = 4 px x 8 co (x read once per octet), NT stores.
// ---------------------------------------------------------------------------
__global__ void conv1x1(const float* __restrict__ x, const float* __restrict__ w,
                        const float* __restrict__ bias, float* __restrict__ out) {
    int i  = blockIdx.x * 256 + threadIdx.x;   // 24*4096*8 = 786,432
    int p4 = i & 4095;
    int oc = (i >> 12) & 7;
    int f  = i >> 15;
    const float4* xb = reinterpret_cast<const float4*>(x + (long)f * 3 * HW);
    float4 x0 = xb[p4];
    float4 x1 = xb[p4 + 4096];
    float4 x2 = xb[p4 + 8192];
    f32x4* ob = (f32x4*)out + ((long)f * 64 << 12) + p4;
    #pragma unroll
    for (int j = 0; j < 8; ++j) {
        int co = oc * 8 + j;
        float w0 = w[co * 3], w1 = w[co * 3 + 1], w2 = w[co * 3 + 2];
        float bv = bias[co];
        f32x4 o;
        o[0] = bv + x0.x * w0 + x1.x * w1 + x2.x * w2;
        o[1] = bv + x0.y * w0 + x1.y * w1 + x2.y * w2;
        o[2] = bv + x0.z * w0 + x1.z * w1 + x2.z * w2;
        o[3] = bv + x0.w * w0 + x1.w * w1 + x2.w * w2;
        __builtin_nontemporal_store(o, ob + ((long)co << 12));
    }
}

// ---------------------------------------------------------------------------
extern "C" void kernel_launch(void* const* d_in, const int* in_sizes, int n_in,
                              void* d_out, int out_size, void* d_ws, size_t ws_size,
                              hipStream_t stream) {
    (void)in_sizes; (void)n_in; (void)out_size; (void)d_ws; (void)ws_size;

    const float* x  = (const float*)d_in[0];
    const float* w1 = (const float*)d_in[4];
    const float* b1 = (const float*)d_in[5];

    float* out = (float*)d_out;

    const long X0_N = 24L * CH * HW;         // 25,165,824 floats (x0 region)
    const long HN   = (long)Bn * CH * HW;    //  4,194,304 floats

    // fp32 NCHW hidden-state OUTPUT slots (written only at the very end)
    float* H[3] = { out + X0_N, out + X0_N + HN, out + X0_N + 2 * HN };

    // scratch carved from the x0 region (overwritten by conv1x1 at the end)
    unsigned short* sc    = (unsigned short*)out;
    unsigned short* ubuf  = sc;                          //  4,194,304 us
    unsigned short* CLH0  = sc + 4194304;                //  CLN each
    unsigned short* CLH1  = CLH0 + CLN;
    unsigned short* CLH2  = CLH1 + CLN;
    unsigned short* clh2  = CLH2 + CLN;                  //  h*r buffer
    unsigned short* clinx = clh2 + CLN;                  //  CLNX (32-ch, L0 x)
    unsigned short* wt    = clinx + CLNX;                //  1,984,512 us
    // end = 27,486,208 us = 13,743,104 f < 25,165,824 f  OK

    const long WT_UR[3] = { 0,      165888, 780288  };
    const long WT_O [3] = { 110592, 575488, 1583104 };

    const int Ks[3]   = { 3, 5, 7 };
    const int C0s[3]  = { CIN, CH, CH };
    const int NCIC[3] = { 3, 4, 4 };

    // zero CLH0..clinx once (halos must stay zero; interiors rewritten)
    hipMemsetAsync(CLH0, 0, (4 * CLN + CLNX) * sizeof(unsigned short), stream);

    // weight transforms (cog-major layout)
    for (int L = 0; L < 3; ++L) {
        const float* wr = (const float*)d_in[6 + 6 * L];
        const float* wu = (const float*)d_in[8 + 6 * L];
        const float* wo = (const float*)d_in[10 + 6 * L];
        int K = Ks[L], C0 = C0s[L], NC = NCIC[L];
        int tot_ur = 2 * K * K * NC * 4 * 64;
        int tot_o  = 1 * K * K * NC * 4 * 64;
        xform_w<<<(tot_ur + 255) / 256, 256, 0, stream>>>(wu, wr, wt + WT_UR[L], K, C0, NC, 2);
        xform_w<<<(tot_o  + 255) / 256, 256, 0, stream>>>(wo, wo, wt + WT_O[L],  K, C0, NC, 1);
    }

    // init CLH[L] from h0 inputs (fp32 NCHW -> bf16 CL)
    unsigned short* CLH[3] = { CLH0, CLH1, CLH2 };
    for (int L = 0; L < 3; ++L)
        build_cl<<<4 * 8 * 64, 256, 0, stream>>>((const float*)d_in[1 + L],
                                                 (long)CH * HW, 64, CLH[L], 8, 64);

    for (int t = 0; t < T; ++t) {
        // L0 input staging (tiny: 3 real channels into 32-stride buffer)
        build_cl<<<4 * 4 * 64, 256, 0, stream>>>(x + (long)t * CIN * HW,
                                                 (long)T * CIN * HW, CIN, clinx, 4, 32);
        {
            const float* br = (const float*)d_in[7];
            const float* bu = (const float*)d_in[9];
            const float* bo = (const float*)d_in[11];
            conv_l0<3, 3, 4, 0, 32><<<dim3(256, 2), 256, 0, stream>>>(
                CLH0, clinx, wt + WT_UR[0], bu, br, ubuf, clh2, nullptr);
            conv_l0<3, 3, 2, 1, 32><<<dim3(512, 1), 256, 0, stream>>>(
                clh2, clinx, wt + WT_O[0], bo, nullptr, ubuf, nullptr, CLH0);
        }
        {
            const float* br = (const float*)d_in[13];
            const float* bu = (const float*)d_in[15];
            const float* bo = (const float*)d_in[17];
            conv_db<5, 0><<<512, 512, 0, stream>>>(
                CLH1, CLH0, wt + WT_UR[1], bu, br, ubuf, clh2, nullptr);
            conv_db<5, 1><<<512, 512, 0, stream>>>(
                clh2, CLH0, wt + WT_O[1], bo, nullptr, ubuf, nullptr, CLH1);
        }
        {
            const float* br = (const float*)d_in[19];
            const float* bu = (const float*)d_in[21];
            const float* bo = (const float*)d_in[23];
            conv_db<7, 0><<<512, 512, 0, stream>>>(
                CLH2, CLH1, wt + WT_UR[2], bu, br, ubuf, clh2, nullptr);
            conv_db<7, 1><<<512, 512, 0, stream>>>(
                clh2, CLH1, wt + WT_O[2], bo, nullptr, ubuf, nullptr, CLH2);
        }
    }

    // final hidden states -> fp32 NCHW output slots
    for (int L = 0; L < 3; ++L)
        unpack_h<<<256, 256, 0, stream>>>(CLH[L], H[L]);

    // x0 projection last — overwrites the scratch region with the real output
    conv1x1<<<786432 / 256, 256, 0, stream>>>(x, w1, b1, out);
}